// Round 2
// 139.973 us; speedup vs baseline: 1.0087x; 1.0087x over previous
//
#include <hip/hip_runtime.h>
#include <hip/hip_fp16.h>

// DSA varlen sparse attention, MI355X — round 12 (= R11 resubmit; infra flake).
// R10 post-mortem: dur 54us with VALUBusy 62%, L2 gather at 57% of ceiling,
// VGPR=32 -> neither pipe saturated; the kernel is LATENCY-bound. The per-row
// chain (readlane -> L2 load ~200cyc -> 2 fdot2 -> 4 dep DPP adds -> v_exp ->
// fma) was executed serially per row with <=2 loads in flight.
// R12: (1) explicit 4-row software pipeline, distance-4 prefetch (8x uint4
// buffers, 32 VGPR of load headroom), 4 independent compute chains per step;
// (2) per-row-slot accumulators (4x S, 4x half2 pairs) to break serial
// accumulation chains, tree-combined at the end;
// (3) selector scores loaded ONCE per lane (coalesced) and routed per-row via
// readlane — removes 64 broadcast VMEM loads/wave from the critical chain;
// (4) q pre-scaled by 0.125*log2e, raw v_exp_f32 (exp2) via inline asm;
// (5) pipeline steps emitted via template<int R> so every __shfl lane index is
// a compile-time literal -> guaranteed v_readlane_b32 (no ds_bpermute).

#define T_TOK 4096
#define NH    16
#define HD    64
#define KSEL  64
#define ROWS  (T_TOK * NH)             // 65536 row-heads

typedef _Float16 h2v __attribute__((ext_vector_type(2)));

static __device__ __forceinline__ h2v u2h2v(unsigned u) {
    return __builtin_bit_cast(h2v, u);
}
static __device__ __forceinline__ __half2 u2h2(unsigned u) {
    return __builtin_bit_cast(__half2, u);
}
static __device__ __forceinline__ h2v f2h2v(float a, float b) {
    __half2 t = __floats2half2_rn(a, b);   // v_cvt_pkrtz_f16_f32
    return __builtin_bit_cast(h2v, t);
}
// DPP adds: 0xB1=xor1  0x4E=xor2  0x141=row_half_mirror(xor4 on quad-uniform)
// 0x140=row_mirror(xor8 on 8-uniform) — all within 16-lane DPP rows.
template<int CTRL>
static __device__ __forceinline__ float dpp_addf(float x) {
    const int s = __builtin_amdgcn_update_dpp(
        0, __builtin_bit_cast(int, x), CTRL, 0xF, 0xF, true);
    return x + __builtin_bit_cast(float, s);
}
// raw 2^x (v_exp_f32) — input already scaled by log2e
static __device__ __forceinline__ float exp2_hw(float x) {
    float r;
    asm("v_exp_f32 %0, %1" : "=v"(r) : "v"(x));
    return r;
}

// ---- cvt pre-pass: fp32 K,V -> interleaved fp16 KV.
// Layout: row-head rh, chunk c (0..15): uint4 = {K[rh,4c..4c+3], V[rh,4c..4c+3]}
// each as 4 fp16. One row-head = 16 uint4 = 256B; 4-head group = 1KB contig.
__global__ __launch_bounds__(256) void cvt_kv(
    const float* __restrict__ kM, const float* __restrict__ vM,
    uint4* __restrict__ kvH)
{
    const int i  = blockIdx.x * blockDim.x + threadIdx.x;   // ROWS*16 threads
    const int rh = i >> 4;
    const int c  = i & 15;
    const float4 fk = *(const float4*)(kM + rh * HD + c * 4);
    const float4 fv = *(const float4*)(vM + rh * HD + c * 4);
    uint4 o;
    o.x = __builtin_bit_cast(unsigned, __floats2half2_rn(fk.x, fk.y));
    o.y = __builtin_bit_cast(unsigned, __floats2half2_rn(fk.z, fk.w));
    o.z = __builtin_bit_cast(unsigned, __floats2half2_rn(fv.x, fv.y));
    o.w = __builtin_bit_cast(unsigned, __floats2half2_rn(fv.z, fv.w));
    kvH[i] = o;
}

// pipeline state bundled so template steps can mutate it
struct PState {
    h2v q01, q23;
    float scl;
    int gbase, lane;
    float s0, s1, s2, s3;
    __half2 a00, a01, a10, a11, a20, a21, a30, a31;
    const uint4* __restrict__ kvH;
};

template<int RR>
static __device__ __forceinline__ uint4 loadkv(const PState& st) {
    // literal lane -> v_readlane_b32; one dwordx4 covers 1KB contiguous
    return st.kvH[(unsigned)__shfl(st.gbase, RR, 64) + st.lane];
}

template<int RR>
static __device__ __forceinline__ void proc(PState& st, const uint4 kv,
                                            float& SA, __half2& A0, __half2& A1) {
    float p = __builtin_amdgcn_fdot2(u2h2v(kv.x), st.q01, 0.f, false);
    p = __builtin_amdgcn_fdot2(u2h2v(kv.y), st.q23, p, false);
    p = dpp_addf<0xB1>(p);   // xor1
    p = dpp_addf<0x4E>(p);   // xor2
    p = dpp_addf<0x141>(p);  // xor4
    p = dpp_addf<0x140>(p);  // xor8
    const float w = exp2_hw(p) * __shfl(st.scl, RR, 64);
    SA += w;
    const __half2 w2 = __floats2half2_rn(w, w);
    A0 = __hfma2(w2, u2h2(kv.z), A0);
    A1 = __hfma2(w2, u2h2(kv.w), A1);
}

// one pipeline stage: process rows R..R+3 (already in kv0..kv3) while
// prefetching rows R+4..R+7; recurse to next stage.
template<int R>
static __device__ __forceinline__ void stage(PState& st, uint4 kv0, uint4 kv1,
                                             uint4 kv2, uint4 kv3) {
    if constexpr (R + 4 < KSEL) {
        uint4 n0 = loadkv<R + 4>(st), n1 = loadkv<R + 5>(st),
              n2 = loadkv<R + 6>(st), n3 = loadkv<R + 7>(st);
        proc<R + 0>(st, kv0, st.s0, st.a00, st.a01);
        proc<R + 1>(st, kv1, st.s1, st.a10, st.a11);
        proc<R + 2>(st, kv2, st.s2, st.a20, st.a21);
        proc<R + 3>(st, kv3, st.s3, st.a30, st.a31);
        stage<R + 4>(st, n0, n1, n2, n3);
    } else {
        proc<R + 0>(st, kv0, st.s0, st.a00, st.a01);
        proc<R + 1>(st, kv1, st.s1, st.a10, st.a11);
        proc<R + 2>(st, kv2, st.s2, st.a20, st.a21);
        proc<R + 3>(st, kv3, st.s3, st.a30, st.a31);
    }
}

// ---------------- main kernel: 1 token x 4 heads per wave ----------------
__global__ __launch_bounds__(256) void dsa_sparse_attn(
    const float* __restrict__ qM,
    const uint4* __restrict__ kvH,
    const int*   __restrict__ cu,
    const int*   __restrict__ tidx,
    const float* __restrict__ tsc,
    float*       __restrict__ out,
    int num_docs)
{
    const int wave = threadIdx.x >> 6;
    const int lane = threadIdx.x & 63;

    // 4096 blocks. slice = (doc, head-group): 16 slices, 2 per XCD.
    // Slice working set (fp16 K+V, 4 heads, 1024 rows) = 1 MB << 4 MiB L2.
    const int b     = blockIdx.x;
    const int xcd   = b & 7;
    const int j     = b >> 3;           // 0..511
    const int tb    = j & 255;          // token block within slice
    const int sw    = j >> 8;           // 0..1
    const int slice = xcd + (sw << 3);  // 0..15
    const int hg    = slice & 3;
    const int doc   = slice >> 2;
    const int h0    = hg << 2;
    const int t     = doc * (T_TOK / 4) + tb * 4 + wave;

    // --- doc segment (wave-uniform; swizzle's doc notion is only a t-map,
    // correctness comes from this cu lookup) ---
    int seg = 0;
    for (int i = 1; i < num_docs; ++i)
        if (t >= cu[i]) seg = i;
    const int start = cu[seg];
    const int len   = cu[seg + 1] - start;

    // --- per-lane gather index (k = lane), clamped ---
    int loc = tidx[t * KSEL + lane] - start;
    loc = loc < 0 ? 0 : (loc > len - 1 ? len - 1 : loc);
    const int g = start + loc;            // selected row for k = lane

    const int lh = lane >> 4;    // head within group (0..3)
    const int ld = lane & 15;    // dim chunk (4 dims each)

    // --- q chunk, pre-scaled by D^-0.5 * log2(e), converted fp16 ---
    const float qs = 0.125f * 1.44269504088896f;
    const float4 qf = *(const float4*)(qM + (t * NH + h0 + lh) * HD + ld * 4);

    PState st;
    st.q01 = f2h2v(qf.x * qs, qf.y * qs);
    st.q23 = f2h2v(qf.z * qs, qf.w * qs);
    st.scl = tsc[t * KSEL + lane];        // selector score for k = lane
    st.gbase = (g * NH + h0) << 4;        // per-lane row base (uint4 units)
    st.lane = lane;
    st.kvH = kvH;
    st.s0 = st.s1 = st.s2 = st.s3 = 0.f;
    st.a00 = st.a01 = st.a10 = st.a11 = u2h2(0u);
    st.a20 = st.a21 = st.a30 = st.a31 = u2h2(0u);

    // 4-row software pipeline, distance-4 prefetch (8 uint4 buffers live)
    uint4 kv0 = loadkv<0>(st), kv1 = loadkv<1>(st),
          kv2 = loadkv<2>(st), kv3 = loadkv<3>(st);
    stage<0>(st, kv0, kv1, kv2, kv3);

    const float S2 = (st.s0 + st.s1) + (st.s2 + st.s3);
    const float inv = __builtin_amdgcn_rcpf(S2);
    const __half2 acc0 = __hadd2(__hadd2(st.a00, st.a10), __hadd2(st.a20, st.a30));
    const __half2 acc1 = __hadd2(__hadd2(st.a01, st.a11), __hadd2(st.a21, st.a31));

    // Each lane owns out[t, h0+lh, 4ld..4ld+3] — no cross-lane reduction.
    const float2 f0 = __half22float2(acc0);
    const float2 f1 = __half22float2(acc1);
    *(float4*)(out + (t * NH + h0 + lh) * HD + ld * 4) =
        make_float4(f0.x * inv, f0.y * inv, f1.x * inv, f1.y * inv);
}

extern "C" void kernel_launch(void* const* d_in, const int* in_sizes, int n_in,
                              void* d_out, int out_size, void* d_ws, size_t ws_size,
                              hipStream_t stream) {
    const float* q   = (const float*)d_in[0];
    const float* k   = (const float*)d_in[1];
    const float* v   = (const float*)d_in[2];
    const int*   cu  = (const int*)d_in[3];
    const int*   ti  = (const int*)d_in[4];
    const float* ts  = (const float*)d_in[5];
    float*       out = (float*)d_out;
    const int num_docs = in_sizes[3] - 1;

    uint4* kvH = (uint4*)d_ws;    // ROWS * 256B = 16.8 MB

    hipLaunchKernelGGL(cvt_kv, dim3(ROWS * 16 / 256), dim3(256), 0, stream,
                       k, v, kvH);

    // 1 token x 4 heads per wave -> 16384 waves -> 4096 blocks
    hipLaunchKernelGGL(dsa_sparse_attn, dim3(4096), dim3(256), 0, stream,
                       q, kvH, cu, ti, ts, out, num_docs);
}